// Round 1
// baseline (586.217 us; speedup 1.0000x reference)
//
#include <hip/hip_runtime.h>
#include <hip/hip_bf16.h>

typedef __bf16 bf16;
typedef __attribute__((ext_vector_type(8))) __bf16 bf16x8;
typedef __attribute__((ext_vector_type(4))) float f32x4;

static_assert(sizeof(bf16x8) == 16, "bf16x8 must be 16B");

constexpr int N_NODES = 10000;
constexpr int N_EDGES = 320000;
constexpr int KPAD    = 264;   // LDS row stride (bf16 elems): 528B -> row-to-row bank offset 4, 16 rows => 2-way (free)

__device__ __forceinline__ float silu_f(float x) { return x / (1.0f + __expf(-x)); }

// ---- wave-level 64x64 MFMA GEMM, K=256, A in LDS [64 x KPAD], BT global [.. x b_stride] (row n, contiguous k)
__device__ __forceinline__ void mfma_64x64_k256(const bf16* A, const bf16* BT, int b_stride,
                                                int r, int q, f32x4 acc[4][4]) {
  for (int k0 = 0; k0 < 256; k0 += 32) {
    bf16x8 a[4], b[4];
#pragma unroll
    for (int mi = 0; mi < 4; ++mi)
      a[mi] = *(const bf16x8*)(A + (16 * mi + r) * KPAD + k0 + q * 8);
#pragma unroll
    for (int ni = 0; ni < 4; ++ni)
      b[ni] = *(const bf16x8*)(BT + (size_t)(16 * ni + r) * b_stride + k0 + q * 8);
#pragma unroll
    for (int mi = 0; mi < 4; ++mi)
#pragma unroll
      for (int ni = 0; ni < 4; ++ni)
        acc[mi][ni] = __builtin_amdgcn_mfma_f32_16x16x32_bf16(a[mi], b[ni], acc[mi][ni], 0, 0, 0);
  }
}

// ---- prep: h -> bf16; transpose+convert weights to bf16 [n][k]
__global__ __launch_bounds__(256) void prep_kernel(
    const float* __restrict__ h, const float* __restrict__ We1, const float* __restrict__ We2,
    const float* __restrict__ Wn1, const float* __restrict__ Wn2, const float* __restrict__ Wc1,
    bf16* __restrict__ Hb, bf16* __restrict__ We1T, bf16* __restrict__ Wn1T,
    bf16* __restrict__ We2T, bf16* __restrict__ Wn2T, bf16* __restrict__ Wc1T) {
  int bid = blockIdx.x, tid = threadIdx.x;
  if (bid < 10000) { int i = bid * 256 + tid; Hb[i] = (bf16)h[i]; return; }
  int t = (bid - 10000) * 256 + tid;
  if (t < 131072) { int k = t >> 8, j = t & 255; We1T[j * 512 + k] = (bf16)We1[k * 256 + j]; return; }
  t -= 131072;
  if (t < 131072) { int k = t >> 8, j = t & 255; Wn1T[j * 512 + k] = (bf16)Wn1[k * 256 + j]; return; }
  t -= 131072;
  if (t < 65536) { int k = t >> 8, j = t & 255; We2T[j * 256 + k] = (bf16)We2[k * 256 + j]; return; }
  t -= 65536;
  if (t < 65536) { int k = t >> 8, j = t & 255; Wn2T[j * 256 + k] = (bf16)Wn2[k * 256 + j]; return; }
  t -= 65536;
  if (t < 65536) { int k = t >> 8, j = t & 255; Wc1T[j * 256 + k] = (bf16)Wc1[k * 256 + j]; return; }
}

// ---- P/Q GEMM: [10000x256] = Hb @ We1T-slice.  grid.y: 0->P (k 0..255), 1->Q (k 256..511)
__global__ __launch_bounds__(256, 2) void gemm_pq(const bf16* __restrict__ Hb,
                                                  const bf16* __restrict__ We1T,
                                                  bf16* __restrict__ P, bf16* __restrict__ Q) {
  int tid = threadIdx.x, w = tid >> 6, lane = tid & 63, r = lane & 15, q = lane >> 4;
  int m0 = blockIdx.x * 64;
  const bf16* BT = We1T + (blockIdx.y ? 256 : 0) + (size_t)(w * 64) * 512;
  bf16* OUT = blockIdx.y ? Q : P;
  f32x4 acc[4][4];
#pragma unroll
  for (int mi = 0; mi < 4; ++mi)
#pragma unroll
    for (int ni = 0; ni < 4; ++ni) acc[mi][ni] = (f32x4){0.f, 0.f, 0.f, 0.f};

  for (int k0 = 0; k0 < 256; k0 += 32) {
    bf16x8 a[4], b[4];
#pragma unroll
    for (int mi = 0; mi < 4; ++mi) {
      int m = m0 + 16 * mi + r; if (m > N_NODES - 1) m = N_NODES - 1;
      a[mi] = *(const bf16x8*)(Hb + (size_t)m * 256 + k0 + q * 8);
    }
#pragma unroll
    for (int ni = 0; ni < 4; ++ni)
      b[ni] = *(const bf16x8*)(BT + (size_t)(16 * ni + r) * 512 + k0 + q * 8);
#pragma unroll
    for (int mi = 0; mi < 4; ++mi)
#pragma unroll
      for (int ni = 0; ni < 4; ++ni)
        acc[mi][ni] = __builtin_amdgcn_mfma_f32_16x16x32_bf16(a[mi], b[ni], acc[mi][ni], 0, 0, 0);
  }
#pragma unroll
  for (int ni = 0; ni < 4; ++ni) {
    int n = w * 64 + 16 * ni + (lane & 15);
#pragma unroll
    for (int mi = 0; mi < 4; ++mi)
#pragma unroll
      for (int rg = 0; rg < 4; ++rg) {
        int m = m0 + 16 * mi + q * 4 + rg;
        if (m < N_NODES) OUT[(size_t)m * 256 + n] = (bf16)acc[mi][ni][rg];
      }
  }
}

// ---- edge kernel: 64 edges/block
__global__ __launch_bounds__(256, 2) void edge_kernel(
    const float* __restrict__ coord, const int* __restrict__ eidx,
    const float* __restrict__ We1, const float* __restrict__ be1,
    const float* __restrict__ be2, const float* __restrict__ bc1,
    const float* __restrict__ Wc2, const float* __restrict__ bc2,
    const bf16* __restrict__ P, const bf16* __restrict__ Q,
    const bf16* __restrict__ We2T, const bf16* __restrict__ Wc1T,
    float* __restrict__ agg_h, float* __restrict__ agg_c, float* __restrict__ cnt) {
  __shared__ __align__(16) bf16 buf0[64 * KPAD];
  __shared__ __align__(16) bf16 buf1[64 * KPAD];
  __shared__ int s_row[64], s_col[64];
  __shared__ float s_rad[64], s_cd[64][3], s_part[64][4];

  int tid = threadIdx.x;
  int e0 = blockIdx.x * 64;
  int w = tid >> 6, lane = tid & 63, r = lane & 15, q = lane >> 4;

  if (tid < 64) {
    int e = e0 + tid;
    int ri = eidx[e], ci = eidx[N_EDGES + e];
    s_row[tid] = ri; s_col[tid] = ci;
    float dx = coord[3 * ri + 0] - coord[3 * ci + 0];
    float dy = coord[3 * ri + 1] - coord[3 * ci + 1];
    float dz = coord[3 * ri + 2] - coord[3 * ci + 2];
    s_cd[tid][0] = dx; s_cd[tid][1] = dy; s_cd[tid][2] = dz;
    s_rad[tid] = dx * dx + dy * dy + dz * dz;
  }
  __syncthreads();

  // e1 = silu(P[row] + Q[col] + radial*We1[512] + be1) -> buf0 (bf16)
  {
    float w512 = We1[512 * 256 + tid];
    float b1 = be1[tid];
#pragma unroll 4
    for (int e = 0; e < 64; ++e) {
      int ri = s_row[e], ci = s_col[e];
      float z = (float)P[(size_t)ri * 256 + tid] + (float)Q[(size_t)ci * 256 + tid]
              + s_rad[e] * w512 + b1;
      buf0[e * KPAD + tid] = (bf16)silu_f(z);
    }
  }
  __syncthreads();

  // GEMM1: edge_feat = silu(e1 @ We2 + be2) -> buf1, + atomics into agg_h
  {
    f32x4 acc[4][4];
#pragma unroll
    for (int mi = 0; mi < 4; ++mi)
#pragma unroll
      for (int ni = 0; ni < 4; ++ni) acc[mi][ni] = (f32x4){0.f, 0.f, 0.f, 0.f};
    mfma_64x64_k256(buf0, We2T + (size_t)(w * 64) * 256, 256, r, q, acc);
#pragma unroll
    for (int ni = 0; ni < 4; ++ni) {
      int n = w * 64 + 16 * ni + (lane & 15);
      float bv = be2[n];
#pragma unroll
      for (int mi = 0; mi < 4; ++mi)
#pragma unroll
        for (int rg = 0; rg < 4; ++rg) {
          int m = 16 * mi + q * 4 + rg;
          float v = silu_f(acc[mi][ni][rg] + bv);
          buf1[m * KPAD + n] = (bf16)v;
          atomicAdd(&agg_h[(size_t)s_row[m] * 256 + n], v);
        }
    }
  }
  __syncthreads();

  // GEMM2: c1 = silu(edge_feat @ Wc1 + bc1) -> buf0
  {
    f32x4 acc[4][4];
#pragma unroll
    for (int mi = 0; mi < 4; ++mi)
#pragma unroll
      for (int ni = 0; ni < 4; ++ni) acc[mi][ni] = (f32x4){0.f, 0.f, 0.f, 0.f};
    mfma_64x64_k256(buf1, Wc1T + (size_t)(w * 64) * 256, 256, r, q, acc);
#pragma unroll
    for (int ni = 0; ni < 4; ++ni) {
      int n = w * 64 + 16 * ni + (lane & 15);
      float bv = bc1[n];
#pragma unroll
      for (int mi = 0; mi < 4; ++mi)
#pragma unroll
        for (int rg = 0; rg < 4; ++rg) {
          int m = 16 * mi + q * 4 + rg;
          buf0[m * KPAD + n] = (bf16)silu_f(acc[mi][ni][rg] + bv);
        }
    }
  }
  __syncthreads();

  // scalar = c1 @ Wc2 + bc2 ; coord atomics
  {
    int e = tid >> 2, p = tid & 3;
    float s = 0.f;
#pragma unroll
    for (int kk = 0; kk < 64; kk += 8) {
      bf16x8 v = *(const bf16x8*)(buf0 + e * KPAD + p * 64 + kk);
#pragma unroll
      for (int j = 0; j < 8; ++j) s += (float)v[j] * Wc2[p * 64 + kk + j];
    }
    s_part[e][p] = s;
  }
  __syncthreads();
  if (tid < 64) {
    float s = s_part[tid][0] + s_part[tid][1] + s_part[tid][2] + s_part[tid][3] + bc2[0];
    int ri = s_row[tid];
    atomicAdd(&agg_c[3 * ri + 0], s_cd[tid][0] * s);
    atomicAdd(&agg_c[3 * ri + 1], s_cd[tid][1] * s);
    atomicAdd(&agg_c[3 * ri + 2], s_cd[tid][2] * s);
    atomicAdd(&cnt[ri], 1.0f);
  }
}

// ---- post: agg_h -> bf16 ; coord_out = coord + agg_c / max(cnt,1)
__global__ __launch_bounds__(256) void post_kernel(
    const float* __restrict__ agg_h, bf16* __restrict__ Ab,
    const float* __restrict__ coord, const float* __restrict__ agg_c,
    const float* __restrict__ cnt, float* __restrict__ coord_out) {
  int bid = blockIdx.x, tid = threadIdx.x;
  if (bid < 10000) { int i = bid * 256 + tid; Ab[i] = (bf16)agg_h[i]; return; }
  int t = (bid - 10000) * 256 + tid;
  if (t < 30000) {
    float c = cnt[t / 3]; if (c < 1.f) c = 1.f;
    coord_out[t] = coord[t] + agg_c[t] / c;
  }
}

// ---- node kernel: h_out = silu([h|agg_h] @ Wn1 + bn1) @ Wn2 + bn2
__global__ __launch_bounds__(256, 2) void node_kernel(
    const bf16* __restrict__ Hb, const bf16* __restrict__ Ab,
    const bf16* __restrict__ Wn1T, const bf16* __restrict__ Wn2T,
    const float* __restrict__ bn1, const float* __restrict__ bn2,
    float* __restrict__ h_out) {
  __shared__ __align__(16) bf16 buf[64 * KPAD];
  int tid = threadIdx.x, w = tid >> 6, lane = tid & 63, r = lane & 15, q = lane >> 4;
  int m0 = blockIdx.x * 64;
  f32x4 acc[4][4];
#pragma unroll
  for (int mi = 0; mi < 4; ++mi)
#pragma unroll
    for (int ni = 0; ni < 4; ++ni) acc[mi][ni] = (f32x4){0.f, 0.f, 0.f, 0.f};

  const bf16* BT1 = Wn1T + (size_t)(w * 64) * 512;
  // layer1 part A: h (k 0..255)
  for (int k0 = 0; k0 < 256; k0 += 32) {
    bf16x8 a[4], b[4];
#pragma unroll
    for (int mi = 0; mi < 4; ++mi) {
      int m = m0 + 16 * mi + r; if (m > N_NODES - 1) m = N_NODES - 1;
      a[mi] = *(const bf16x8*)(Hb + (size_t)m * 256 + k0 + q * 8);
    }
#pragma unroll
    for (int ni = 0; ni < 4; ++ni)
      b[ni] = *(const bf16x8*)(BT1 + (size_t)(16 * ni + r) * 512 + k0 + q * 8);
#pragma unroll
    for (int mi = 0; mi < 4; ++mi)
#pragma unroll
      for (int ni = 0; ni < 4; ++ni)
        acc[mi][ni] = __builtin_amdgcn_mfma_f32_16x16x32_bf16(a[mi], b[ni], acc[mi][ni], 0, 0, 0);
  }
  // layer1 part B: agg_h (k 256..511)
  for (int k0 = 0; k0 < 256; k0 += 32) {
    bf16x8 a[4], b[4];
#pragma unroll
    for (int mi = 0; mi < 4; ++mi) {
      int m = m0 + 16 * mi + r; if (m > N_NODES - 1) m = N_NODES - 1;
      a[mi] = *(const bf16x8*)(Ab + (size_t)m * 256 + k0 + q * 8);
    }
#pragma unroll
    for (int ni = 0; ni < 4; ++ni)
      b[ni] = *(const bf16x8*)(BT1 + (size_t)(16 * ni + r) * 512 + 256 + k0 + q * 8);
#pragma unroll
    for (int mi = 0; mi < 4; ++mi)
#pragma unroll
      for (int ni = 0; ni < 4; ++ni)
        acc[mi][ni] = __builtin_amdgcn_mfma_f32_16x16x32_bf16(a[mi], b[ni], acc[mi][ni], 0, 0, 0);
  }
  // bias + silu -> LDS
#pragma unroll
  for (int ni = 0; ni < 4; ++ni) {
    int n = w * 64 + 16 * ni + (lane & 15);
    float bv = bn1[n];
#pragma unroll
    for (int mi = 0; mi < 4; ++mi)
#pragma unroll
      for (int rg = 0; rg < 4; ++rg) {
        int m = 16 * mi + q * 4 + rg;
        buf[m * KPAD + n] = (bf16)silu_f(acc[mi][ni][rg] + bv);
      }
  }
  __syncthreads();
  // layer2
#pragma unroll
  for (int mi = 0; mi < 4; ++mi)
#pragma unroll
    for (int ni = 0; ni < 4; ++ni) acc[mi][ni] = (f32x4){0.f, 0.f, 0.f, 0.f};
  mfma_64x64_k256(buf, Wn2T + (size_t)(w * 64) * 256, 256, r, q, acc);
#pragma unroll
  for (int ni = 0; ni < 4; ++ni) {
    int n = w * 64 + 16 * ni + (lane & 15);
    float bv = bn2[n];
#pragma unroll
    for (int mi = 0; mi < 4; ++mi)
#pragma unroll
      for (int rg = 0; rg < 4; ++rg) {
        int m = m0 + 16 * mi + q * 4 + rg;
        if (m < N_NODES) h_out[(size_t)m * 256 + n] = acc[mi][ni][rg] + bv;
      }
  }
}

extern "C" void kernel_launch(void* const* d_in, const int* in_sizes, int n_in,
                              void* d_out, int out_size, void* d_ws, size_t ws_size,
                              hipStream_t stream) {
  const float* h     = (const float*)d_in[0];
  const float* coord = (const float*)d_in[1];
  const int*   eidx  = (const int*)d_in[2];
  const float* We1 = (const float*)d_in[3];
  const float* be1 = (const float*)d_in[4];
  const float* We2 = (const float*)d_in[5];
  const float* be2 = (const float*)d_in[6];
  const float* Wn1 = (const float*)d_in[7];
  const float* bn1 = (const float*)d_in[8];
  const float* Wn2 = (const float*)d_in[9];
  const float* bn2 = (const float*)d_in[10];
  const float* Wc1 = (const float*)d_in[11];
  const float* bc1 = (const float*)d_in[12];
  const float* Wc2 = (const float*)d_in[13];
  const float* bc2 = (const float*)d_in[14];

  char* ws = (char*)d_ws;
  float* agg_h = (float*)(ws + 0);          // 10,240,000
  float* agg_c = (float*)(ws + 10240000);   // 120,000
  float* cnt   = (float*)(ws + 10360000);   // 40,000
  bf16* Hb   = (bf16*)(ws + 10400000);      // 5,120,000
  bf16* P    = (bf16*)(ws + 15520000);      // 5,120,000
  bf16* Q    = (bf16*)(ws + 20640000);      // 5,120,000
  bf16* Ab   = (bf16*)(ws + 25760000);      // 5,120,000
  bf16* We1T = (bf16*)(ws + 30880000);      // 262,144
  bf16* Wn1T = (bf16*)(ws + 31142144);      // 262,144
  bf16* We2T = (bf16*)(ws + 31404288);      // 131,072
  bf16* Wn2T = (bf16*)(ws + 31535360);      // 131,072
  bf16* Wc1T = (bf16*)(ws + 31666432);      // 131,072

  float* h_out = (float*)d_out;
  float* coord_out = h_out + (size_t)N_NODES * 256;

  hipMemsetAsync(agg_h, 0, 10400000, stream);
  prep_kernel<<<11792, 256, 0, stream>>>(h, We1, We2, Wn1, Wn2, Wc1,
                                         Hb, We1T, Wn1T, We2T, Wn2T, Wc1T);
  gemm_pq<<<dim3(157, 2), 256, 0, stream>>>(Hb, We1T, P, Q);
  edge_kernel<<<5000, 256, 0, stream>>>(coord, eidx, We1, be1, be2, bc1, Wc2, bc2,
                                        P, Q, We2T, Wc1T, agg_h, agg_c, cnt);
  post_kernel<<<10118, 256, 0, stream>>>(agg_h, Ab, coord, agg_c, cnt, coord_out);
  node_kernel<<<157, 256, 0, stream>>>(Hb, Ab, Wn1T, Wn2T, bn1, bn2, h_out);
}

// Round 2
// 472.680 us; speedup vs baseline: 1.2402x; 1.2402x over previous
//
#include <hip/hip_runtime.h>
#include <hip/hip_bf16.h>

typedef __bf16 bf16;
typedef __attribute__((ext_vector_type(8))) __bf16 bf16x8;
typedef __attribute__((ext_vector_type(4))) float f32x4;

static_assert(sizeof(bf16x8) == 16, "bf16x8 must be 16B");

constexpr int N_NODES = 10000;
constexpr int N_EDGES = 320000;
constexpr int KPAD    = 264;   // LDS row stride (bf16): 528B/row -> 2-way bank aliasing (free per m136)

__device__ __forceinline__ float silu_f(float x) { return x / (1.0f + __expf(-x)); }

// ---- wave-level 64x64 MFMA GEMM, K=256, A in LDS [64 x KPAD], BT global (row n, contiguous k)
__device__ __forceinline__ void mfma_64x64_k256(const bf16* A, const bf16* BT, int b_stride,
                                                int r, int q, f32x4 acc[4][4]) {
  for (int k0 = 0; k0 < 256; k0 += 32) {
    bf16x8 a[4], b[4];
#pragma unroll
    for (int mi = 0; mi < 4; ++mi)
      a[mi] = *(const bf16x8*)(A + (16 * mi + r) * KPAD + k0 + q * 8);
#pragma unroll
    for (int ni = 0; ni < 4; ++ni)
      b[ni] = *(const bf16x8*)(BT + (size_t)(16 * ni + r) * b_stride + k0 + q * 8);
#pragma unroll
    for (int mi = 0; mi < 4; ++mi)
#pragma unroll
      for (int ni = 0; ni < 4; ++ni)
        acc[mi][ni] = __builtin_amdgcn_mfma_f32_16x16x32_bf16(a[mi], b[ni], acc[mi][ni], 0, 0, 0);
  }
}

// ---- prep: h -> bf16; transpose+convert weights to bf16 [n][k]
__global__ __launch_bounds__(256) void prep_kernel(
    const float* __restrict__ h, const float* __restrict__ We1, const float* __restrict__ We2,
    const float* __restrict__ Wn1, const float* __restrict__ Wn2, const float* __restrict__ Wc1,
    bf16* __restrict__ Hb, bf16* __restrict__ We1T, bf16* __restrict__ Wn1T,
    bf16* __restrict__ We2T, bf16* __restrict__ Wn2T, bf16* __restrict__ Wc1T) {
  int bid = blockIdx.x, tid = threadIdx.x;
  if (bid < 10000) { int i = bid * 256 + tid; Hb[i] = (bf16)h[i]; return; }
  int t = (bid - 10000) * 256 + tid;
  if (t < 131072) { int k = t >> 8, j = t & 255; We1T[j * 512 + k] = (bf16)We1[k * 256 + j]; return; }
  t -= 131072;
  if (t < 131072) { int k = t >> 8, j = t & 255; Wn1T[j * 512 + k] = (bf16)Wn1[k * 256 + j]; return; }
  t -= 131072;
  if (t < 65536) { int k = t >> 8, j = t & 255; We2T[j * 256 + k] = (bf16)We2[k * 256 + j]; return; }
  t -= 65536;
  if (t < 65536) { int k = t >> 8, j = t & 255; Wn2T[j * 256 + k] = (bf16)Wn2[k * 256 + j]; return; }
  t -= 65536;
  if (t < 65536) { int k = t >> 8, j = t & 255; Wc1T[j * 256 + k] = (bf16)Wc1[k * 256 + j]; return; }
}

// ---- counting sort of edges by row: hist -> scan -> scatter
__global__ __launch_bounds__(256) void hist_kernel(const int* __restrict__ eidx, int* __restrict__ hist) {
  int e = blockIdx.x * 256 + threadIdx.x;
  if (e < N_EDGES) atomicAdd(&hist[eidx[e]], 1);
}

__global__ __launch_bounds__(256) void scan_kernel(const int* __restrict__ hist,
                                                   int* __restrict__ base, int* __restrict__ cursor) {
  __shared__ int partial[256];
  int t = threadIdx.x;
  int s = 0;
#pragma unroll 4
  for (int i = 0; i < 40; ++i) { int idx = t * 40 + i; if (idx < N_NODES) s += hist[idx]; }
  partial[t] = s;
  __syncthreads();
  if (t == 0) { int run = 0; for (int i = 0; i < 256; ++i) { int v = partial[i]; partial[i] = run; run += v; } }
  __syncthreads();
  int run = partial[t];
  for (int i = 0; i < 40; ++i) {
    int idx = t * 40 + i;
    if (idx < N_NODES) { base[idx] = run; cursor[idx] = run; run += hist[idx]; }
  }
}

__global__ __launch_bounds__(256) void scatter_kernel(const int* __restrict__ eidx, int* __restrict__ cursor,
                                                      int* __restrict__ rs, int* __restrict__ cs) {
  int e = blockIdx.x * 256 + threadIdx.x;
  if (e < N_EDGES) {
    int r = eidx[e], c = eidx[N_EDGES + e];
    int p = atomicAdd(&cursor[r], 1);
    rs[p] = r; cs[p] = c;
  }
}

// ---- P/Q GEMM: [10000x256] = Hb @ We1T-slice.  grid.y: 0->P (k 0..255), 1->Q (k 256..511)
__global__ __launch_bounds__(256, 2) void gemm_pq(const bf16* __restrict__ Hb,
                                                  const bf16* __restrict__ We1T,
                                                  bf16* __restrict__ P, bf16* __restrict__ Q) {
  int tid = threadIdx.x, w = tid >> 6, lane = tid & 63, r = lane & 15, q = lane >> 4;
  int m0 = blockIdx.x * 64;
  const bf16* BT = We1T + (blockIdx.y ? 256 : 0) + (size_t)(w * 64) * 512;
  bf16* OUT = blockIdx.y ? Q : P;
  f32x4 acc[4][4];
#pragma unroll
  for (int mi = 0; mi < 4; ++mi)
#pragma unroll
    for (int ni = 0; ni < 4; ++ni) acc[mi][ni] = (f32x4){0.f, 0.f, 0.f, 0.f};

  for (int k0 = 0; k0 < 256; k0 += 32) {
    bf16x8 a[4], b[4];
#pragma unroll
    for (int mi = 0; mi < 4; ++mi) {
      int m = m0 + 16 * mi + r; if (m > N_NODES - 1) m = N_NODES - 1;
      a[mi] = *(const bf16x8*)(Hb + (size_t)m * 256 + k0 + q * 8);
    }
#pragma unroll
    for (int ni = 0; ni < 4; ++ni)
      b[ni] = *(const bf16x8*)(BT + (size_t)(16 * ni + r) * 512 + k0 + q * 8);
#pragma unroll
    for (int mi = 0; mi < 4; ++mi)
#pragma unroll
      for (int ni = 0; ni < 4; ++ni)
        acc[mi][ni] = __builtin_amdgcn_mfma_f32_16x16x32_bf16(a[mi], b[ni], acc[mi][ni], 0, 0, 0);
  }
#pragma unroll
  for (int ni = 0; ni < 4; ++ni) {
    int n = w * 64 + 16 * ni + (lane & 15);
#pragma unroll
    for (int mi = 0; mi < 4; ++mi)
#pragma unroll
      for (int rg = 0; rg < 4; ++rg) {
        int m = m0 + 16 * mi + q * 4 + rg;
        if (m < N_NODES) OUT[(size_t)m * 256 + n] = (bf16)acc[mi][ni][rg];
      }
  }
}

// ---- edge kernel: 64 sorted edges/block, single LDS buffer, segmented aggregation
__global__ __launch_bounds__(256, 4) void edge_kernel(
    const float* __restrict__ coord, const int* __restrict__ rs, const int* __restrict__ cs,
    const float* __restrict__ We1, const float* __restrict__ be1,
    const float* __restrict__ be2, const float* __restrict__ bc1,
    const float* __restrict__ Wc2, const float* __restrict__ bc2,
    const bf16* __restrict__ P, const bf16* __restrict__ Q,
    const bf16* __restrict__ We2T, const bf16* __restrict__ Wc1T,
    float* __restrict__ agg_h, float* __restrict__ agg_c) {
  __shared__ __align__(16) bf16 buf[64 * KPAD];
  __shared__ int s_row[64], s_col[64];
  __shared__ float s_rad[64], s_cd[64][3], s_part[64][4], s_scal[64];

  int tid = threadIdx.x;
  int e0 = blockIdx.x * 64;
  int w = tid >> 6, lane = tid & 63, r = lane & 15, q = lane >> 4;

  if (tid < 64) {
    int e = e0 + tid;
    int ri = rs[e], ci = cs[e];
    s_row[tid] = ri; s_col[tid] = ci;
    float dx = coord[3 * ri + 0] - coord[3 * ci + 0];
    float dy = coord[3 * ri + 1] - coord[3 * ci + 1];
    float dz = coord[3 * ri + 2] - coord[3 * ci + 2];
    s_cd[tid][0] = dx; s_cd[tid][1] = dy; s_cd[tid][2] = dz;
    s_rad[tid] = dx * dx + dy * dy + dz * dz;
  }
  __syncthreads();

  // e1 = silu(P[row] + Q[col] + radial*We1[512] + be1) -> buf (bf16), vectorized 8-wide
  {
    int off = (tid & 31) * 8;        // column group
    int esub = tid >> 5;             // 0..7
    float wv[8], bv[8];
#pragma unroll
    for (int j = 0; j < 8; ++j) { wv[j] = We1[512 * 256 + off + j]; bv[j] = be1[off + j]; }
#pragma unroll
    for (int p = 0; p < 8; ++p) {
      int e = p * 8 + esub;
      int ri = s_row[e], ci = s_col[e];
      bf16x8 pv = *(const bf16x8*)(P + (size_t)ri * 256 + off);
      bf16x8 qv = *(const bf16x8*)(Q + (size_t)ci * 256 + off);
      float rad = s_rad[e];
      bf16x8 o;
#pragma unroll
      for (int j = 0; j < 8; ++j)
        o[j] = (bf16)silu_f((float)pv[j] + (float)qv[j] + rad * wv[j] + bv[j]);
      *(bf16x8*)(buf + e * KPAD + off) = o;
    }
  }
  __syncthreads();

  // GEMM1: edge_feat = silu(e1 @ We2 + be2); acc in regs, then write back into buf
  {
    f32x4 acc[4][4];
#pragma unroll
    for (int mi = 0; mi < 4; ++mi)
#pragma unroll
      for (int ni = 0; ni < 4; ++ni) acc[mi][ni] = (f32x4){0.f, 0.f, 0.f, 0.f};
    mfma_64x64_k256(buf, We2T + (size_t)(w * 64) * 256, 256, r, q, acc);
    __syncthreads();   // all reads of e1 done before overwrite
#pragma unroll
    for (int ni = 0; ni < 4; ++ni) {
      int n = w * 64 + 16 * ni + r;
      float bv = be2[n];
#pragma unroll
      for (int mi = 0; mi < 4; ++mi)
#pragma unroll
        for (int rg = 0; rg < 4; ++rg) {
          int m = 16 * mi + q * 4 + rg;
          buf[m * KPAD + n] = (bf16)silu_f(acc[mi][ni][rg] + bv);
        }
    }
  }
  __syncthreads();

  // agg_h: segmented column-sum over sorted rows (runs are contiguous; branch is block-uniform)
  {
    float s = 0.f;
    int cur = s_row[0];
#pragma unroll 4
    for (int e = 0; e < 64; ++e) {
      int re = s_row[e];
      if (re != cur) { atomicAdd(&agg_h[(size_t)cur * 256 + tid], s); s = 0.f; cur = re; }
      s += (float)buf[e * KPAD + tid];
    }
    atomicAdd(&agg_h[(size_t)cur * 256 + tid], s);
  }

  // GEMM2: c1 = silu(edge_feat @ Wc1 + bc1) -> buf
  {
    f32x4 acc[4][4];
#pragma unroll
    for (int mi = 0; mi < 4; ++mi)
#pragma unroll
      for (int ni = 0; ni < 4; ++ni) acc[mi][ni] = (f32x4){0.f, 0.f, 0.f, 0.f};
    mfma_64x64_k256(buf, Wc1T + (size_t)(w * 64) * 256, 256, r, q, acc);
    __syncthreads();   // reads of edge_feat (MFMA + column-sum) done
#pragma unroll
    for (int ni = 0; ni < 4; ++ni) {
      int n = w * 64 + 16 * ni + r;
      float bv = bc1[n];
#pragma unroll
      for (int mi = 0; mi < 4; ++mi)
#pragma unroll
        for (int rg = 0; rg < 4; ++rg) {
          int m = 16 * mi + q * 4 + rg;
          buf[m * KPAD + n] = (bf16)silu_f(acc[mi][ni][rg] + bv);
        }
    }
  }
  __syncthreads();

  // scalar = c1 @ Wc2 + bc2
  {
    int e = tid >> 2, p = tid & 3;
    float s = 0.f;
#pragma unroll
    for (int kk = 0; kk < 64; kk += 8) {
      bf16x8 v = *(const bf16x8*)(buf + e * KPAD + p * 64 + kk);
#pragma unroll
      for (int j = 0; j < 8; ++j) s += (float)v[j] * Wc2[p * 64 + kk + j];
    }
    s_part[e][p] = s;
  }
  __syncthreads();
  if (tid < 64)
    s_scal[tid] = s_part[tid][0] + s_part[tid][1] + s_part[tid][2] + s_part[tid][3] + bc2[0];
  __syncthreads();

  // coord aggregation: segmented, one lane per xyz component (runs ~2-5 per block)
  if (tid < 3) {
    float s = 0.f;
    int cur = s_row[0];
    for (int e = 0; e < 64; ++e) {
      int re = s_row[e];
      if (re != cur) { atomicAdd(&agg_c[3 * cur + tid], s); s = 0.f; cur = re; }
      s += s_cd[e][tid] * s_scal[e];
    }
    atomicAdd(&agg_c[3 * cur + tid], s);
  }
}

// ---- post: agg_h -> bf16 ; coord_out = coord + agg_c / max(cnt,1)
__global__ __launch_bounds__(256) void post_kernel(
    const float* __restrict__ agg_h, bf16* __restrict__ Ab,
    const float* __restrict__ coord, const float* __restrict__ agg_c,
    const int* __restrict__ hist, float* __restrict__ coord_out) {
  int bid = blockIdx.x, tid = threadIdx.x;
  if (bid < 10000) { int i = bid * 256 + tid; Ab[i] = (bf16)agg_h[i]; return; }
  int t = (bid - 10000) * 256 + tid;
  if (t < 30000) {
    float c = (float)hist[t / 3]; if (c < 1.f) c = 1.f;
    coord_out[t] = coord[t] + agg_c[t] / c;
  }
}

// ---- node kernel: h_out = silu([h|agg_h] @ Wn1 + bn1) @ Wn2 + bn2
__global__ __launch_bounds__(256, 2) void node_kernel(
    const bf16* __restrict__ Hb, const bf16* __restrict__ Ab,
    const bf16* __restrict__ Wn1T, const bf16* __restrict__ Wn2T,
    const float* __restrict__ bn1, const float* __restrict__ bn2,
    float* __restrict__ h_out) {
  __shared__ __align__(16) bf16 buf[64 * KPAD];
  int tid = threadIdx.x, w = tid >> 6, lane = tid & 63, r = lane & 15, q = lane >> 4;
  int m0 = blockIdx.x * 64;
  f32x4 acc[4][4];
#pragma unroll
  for (int mi = 0; mi < 4; ++mi)
#pragma unroll
    for (int ni = 0; ni < 4; ++ni) acc[mi][ni] = (f32x4){0.f, 0.f, 0.f, 0.f};

  const bf16* BT1 = Wn1T + (size_t)(w * 64) * 512;
  for (int k0 = 0; k0 < 256; k0 += 32) {
    bf16x8 a[4], b[4];
#pragma unroll
    for (int mi = 0; mi < 4; ++mi) {
      int m = m0 + 16 * mi + r; if (m > N_NODES - 1) m = N_NODES - 1;
      a[mi] = *(const bf16x8*)(Hb + (size_t)m * 256 + k0 + q * 8);
    }
#pragma unroll
    for (int ni = 0; ni < 4; ++ni)
      b[ni] = *(const bf16x8*)(BT1 + (size_t)(16 * ni + r) * 512 + k0 + q * 8);
#pragma unroll
    for (int mi = 0; mi < 4; ++mi)
#pragma unroll
      for (int ni = 0; ni < 4; ++ni)
        acc[mi][ni] = __builtin_amdgcn_mfma_f32_16x16x32_bf16(a[mi], b[ni], acc[mi][ni], 0, 0, 0);
  }
  for (int k0 = 0; k0 < 256; k0 += 32) {
    bf16x8 a[4], b[4];
#pragma unroll
    for (int mi = 0; mi < 4; ++mi) {
      int m = m0 + 16 * mi + r; if (m > N_NODES - 1) m = N_NODES - 1;
      a[mi] = *(const bf16x8*)(Ab + (size_t)m * 256 + k0 + q * 8);
    }
#pragma unroll
    for (int ni = 0; ni < 4; ++ni)
      b[ni] = *(const bf16x8*)(BT1 + (size_t)(16 * ni + r) * 512 + 256 + k0 + q * 8);
#pragma unroll
    for (int mi = 0; mi < 4; ++mi)
#pragma unroll
      for (int ni = 0; ni < 4; ++ni)
        acc[mi][ni] = __builtin_amdgcn_mfma_f32_16x16x32_bf16(a[mi], b[ni], acc[mi][ni], 0, 0, 0);
  }
#pragma unroll
  for (int ni = 0; ni < 4; ++ni) {
    int n = w * 64 + 16 * ni + (lane & 15);
    float bv = bn1[n];
#pragma unroll
    for (int mi = 0; mi < 4; ++mi)
#pragma unroll
      for (int rg = 0; rg < 4; ++rg) {
        int m = 16 * mi + q * 4 + rg;
        buf[m * KPAD + n] = (bf16)silu_f(acc[mi][ni][rg] + bv);
      }
  }
  __syncthreads();
#pragma unroll
  for (int mi = 0; mi < 4; ++mi)
#pragma unroll
    for (int ni = 0; ni < 4; ++ni) acc[mi][ni] = (f32x4){0.f, 0.f, 0.f, 0.f};
  mfma_64x64_k256(buf, Wn2T + (size_t)(w * 64) * 256, 256, r, q, acc);
#pragma unroll
  for (int ni = 0; ni < 4; ++ni) {
    int n = w * 64 + 16 * ni + (lane & 15);
    float bv = bn2[n];
#pragma unroll
    for (int mi = 0; mi < 4; ++mi)
#pragma unroll
      for (int rg = 0; rg < 4; ++rg) {
        int m = m0 + 16 * mi + q * 4 + rg;
        if (m < N_NODES) h_out[(size_t)m * 256 + n] = acc[mi][ni][rg] + bv;
      }
  }
}

extern "C" void kernel_launch(void* const* d_in, const int* in_sizes, int n_in,
                              void* d_out, int out_size, void* d_ws, size_t ws_size,
                              hipStream_t stream) {
  const float* h     = (const float*)d_in[0];
  const float* coord = (const float*)d_in[1];
  const int*   eidx  = (const int*)d_in[2];
  const float* We1 = (const float*)d_in[3];
  const float* be1 = (const float*)d_in[4];
  const float* We2 = (const float*)d_in[5];
  const float* be2 = (const float*)d_in[6];
  const float* Wn1 = (const float*)d_in[7];
  const float* bn1 = (const float*)d_in[8];
  const float* Wn2 = (const float*)d_in[9];
  const float* bn2 = (const float*)d_in[10];
  const float* Wc1 = (const float*)d_in[11];
  const float* bc1 = (const float*)d_in[12];
  const float* Wc2 = (const float*)d_in[13];
  const float* bc2 = (const float*)d_in[14];

  char* ws = (char*)d_ws;
  float* agg_h = (float*)(ws + 0);          // 10,240,000
  float* agg_c = (float*)(ws + 10240000);   //    120,000
  int*   hist  = (int*)  (ws + 10360000);   //     40,000
  int*   base  = (int*)  (ws + 10400000);   //     40,000
  int*   cursor= (int*)  (ws + 10440000);   //     40,000
  int*   rs    = (int*)  (ws + 10480000);   //  1,280,000
  int*   cs    = (int*)  (ws + 11760000);   //  1,280,000
  bf16* Hb   = (bf16*)(ws + 13040000);      //  5,120,000
  bf16* P    = (bf16*)(ws + 18160000);      //  5,120,000
  bf16* Q    = (bf16*)(ws + 23280000);      //  5,120,000
  bf16* Ab   = (bf16*)(ws + 28400000);      //  5,120,000
  bf16* We1T = (bf16*)(ws + 33520000);      //    262,144
  bf16* Wn1T = (bf16*)(ws + 33782144);      //    262,144
  bf16* We2T = (bf16*)(ws + 34044288);      //    131,072
  bf16* Wn2T = (bf16*)(ws + 34175360);      //    131,072
  bf16* Wc1T = (bf16*)(ws + 34306432);      //    131,072

  float* h_out = (float*)d_out;
  float* coord_out = h_out + (size_t)N_NODES * 256;

  hipMemsetAsync(ws, 0, 10400000, stream);  // agg_h + agg_c + hist
  prep_kernel<<<11792, 256, 0, stream>>>(h, We1, We2, Wn1, Wn2, Wc1,
                                         Hb, We1T, Wn1T, We2T, Wn2T, Wc1T);
  hist_kernel<<<1250, 256, 0, stream>>>(eidx, hist);
  scan_kernel<<<1, 256, 0, stream>>>(hist, base, cursor);
  scatter_kernel<<<1250, 256, 0, stream>>>(eidx, cursor, rs, cs);
  gemm_pq<<<dim3(157, 2), 256, 0, stream>>>(Hb, We1T, P, Q);
  edge_kernel<<<5000, 256, 0, stream>>>(coord, rs, cs, We1, be1, be2, bc1, Wc2, bc2,
                                        P, Q, We2T, Wc1T, agg_h, agg_c);
  post_kernel<<<10118, 256, 0, stream>>>(agg_h, Ab, coord, agg_c, hist, coord_out);
  node_kernel<<<157, 256, 0, stream>>>(Hb, Ab, Wn1T, Wn2T, bn1, bn2, h_out);
}